// Round 3
// baseline (48.864 us; speedup 1.0000x reference)
//
#include <hip/hip_runtime.h>

// trainableBiquad4: y = a * biquad2(biquad1(x)) + c
// x: [B=8, S=4096, D=768] f32. Recurrence along S, independent per (b, d).
//
// R2 -> R3: both rounds plateau at ~4.2 TB/s effective with dword (256 B/wave)
// requests; extra occupancy (R2) bought nothing -> request-rate limited, not
// latency. Fix: float4 per thread (4 channels/thread, 16 B/lane, 1 KB/wave
// request) + 4x ILP from 4 independent IIR chains per thread.
// CHUNK=32, WARM=32 (pole^32 ~ 1e-7 -> exact), 1024 blocks x 192 thr
// = 12 waves/CU. Register A/B double-buffer prefetch, ~1.5 groups in flight.

#define B_ 8
#define S_ 4096
#define D_ 768
#define D4 (D_ / 4)            // 192 float4 per row
#define CHUNK 32
#define WARM 32
#define NCHUNK (S_ / CHUNK)    // 128
#define TPB D4                 // 192 threads = 3 waves
#define G 4                    // steps per prefetch group

__device__ __forceinline__ float4 f4fma(const float4 a, const float4 b, const float4 c) {
    return make_float4(fmaf(a.x, b.x, c.x), fmaf(a.y, b.y, c.y),
                       fmaf(a.z, b.z, c.z), fmaf(a.w, b.w, c.w));
}
__device__ __forceinline__ float4 f4mul(const float4 a, const float4 b) {
    return make_float4(a.x * b.x, a.y * b.y, a.z * b.z, a.w * b.w);
}
__device__ __forceinline__ float4 f4sub(const float4 a, const float4 b) {
    return make_float4(a.x - b.x, a.y - b.y, a.z - b.z, a.w - b.w);
}

__global__ __launch_bounds__(TPB) void biquad4_kernel(
    const float* __restrict__ x,
    const float* __restrict__ Ascale,
    const float* __restrict__ Cshift,
    const float* __restrict__ b1,
    const float* __restrict__ fa1,
    const float* __restrict__ b2,
    const float* __restrict__ fa2,
    float* __restrict__ out)
{
    const int tid   = threadIdx.x;        // 0..191 -> channels 4*tid..4*tid+3
    const int blk   = blockIdx.x;         // 0..1023
    const int chunk = blk % NCHUNK;
    const int b     = blk / NCHUNK;

    const int cs    = chunk * CHUNK;                 // first output t
    const int nwarm = (chunk == 0) ? 0 : WARM;
    const int t0    = cs - nwarm;
    const int ngrp  = (nwarm + CHUNK) / G;           // 16 or 8 (even)
    const int sgrp  = nwarm / G;                     // first storing group

    const float a = Ascale[0];
    const float c = Cshift[0];
    const float4 av = make_float4(a, a, a, a);
    const float4 cv = make_float4(c, c, c, c);

    const float4* b1v  = (const float4*)b1;
    const float4* fa1v = (const float4*)fa1;
    const float4* b2v  = (const float4*)b2;
    const float4* fa2v = (const float4*)fa2;
    const float4 B10 = b1v[tid],  B11 = b1v[D4 + tid],  B12 = b1v[2 * D4 + tid];
    const float4 A11 = fa1v[tid], A12 = fa1v[D4 + tid];
    const float4 B20 = b2v[tid],  B21 = b2v[D4 + tid],  B22 = b2v[2 * D4 + tid];
    const float4 A21 = fa2v[tid], A22 = fa2v[D4 + tid];

    const float4* __restrict__ xp = (const float4*)x + ((size_t)b * S_ + t0) * D4 + tid;
    float4*       __restrict__ op = (float4*)out     + ((size_t)b * S_ + cs) * D4 + tid;

    const float4 zero = make_float4(0.f, 0.f, 0.f, 0.f);
    float4 X1 = zero, X2 = zero;   // section-1 input history
    float4 Y1 = zero, Y2 = zero;   // section-1 output history
    float4 Z1 = zero, Z2 = zero;   // section-2 output history

#define STEP(XT)                                                              \
        {                                                                     \
            const float4 xt = (XT);                                           \
            const float4 yt = f4sub(f4fma(B10, xt, f4fma(B11, X1, f4mul(B12, X2))), \
                                    f4fma(A11, Y1, f4mul(A12, Y2)));          \
            const float4 zt = f4sub(f4fma(B20, yt, f4fma(B21, Y1, f4mul(B22, Y2))), \
                                    f4fma(A21, Z1, f4mul(A22, Z2)));          \
            X2 = X1; X1 = xt;                                                 \
            Y2 = Y1; Y1 = yt;                                                 \
            Z2 = Z1; Z1 = zt;                                                 \
        }

    float4 pA[G], pB[G];

    // prologue: group 0 -> pA
    #pragma unroll
    for (int i = 0; i < G; ++i) pA[i] = xp[(size_t)i * D4];
    xp += (size_t)G * D4;

    for (int g = 0; g < ngrp; g += 2) {
        // load group g+1 -> pB
        if (g + 1 < ngrp) {
            #pragma unroll
            for (int i = 0; i < G; ++i) pB[i] = xp[(size_t)i * D4];
            xp += (size_t)G * D4;
        }
        // compute group g from pA (store iff g >= sgrp; block-uniform branch)
        if (g >= sgrp) {
            #pragma unroll
            for (int i = 0; i < G; ++i) {
                STEP(pA[i]);
                op[(size_t)i * D4] = f4fma(av, Z1, cv);
            }
            op += (size_t)G * D4;
        } else {
            #pragma unroll
            for (int i = 0; i < G; ++i) STEP(pA[i]);
        }
        // load group g+2 -> pA
        if (g + 2 < ngrp) {
            #pragma unroll
            for (int i = 0; i < G; ++i) pA[i] = xp[(size_t)i * D4];
            xp += (size_t)G * D4;
        }
        // compute group g+1 from pB
        if (g + 1 < ngrp) {
            if (g + 1 >= sgrp) {
                #pragma unroll
                for (int i = 0; i < G; ++i) {
                    STEP(pB[i]);
                    op[(size_t)i * D4] = f4fma(av, Z1, cv);
                }
                op += (size_t)G * D4;
            } else {
                #pragma unroll
                for (int i = 0; i < G; ++i) STEP(pB[i]);
            }
        }
    }
#undef STEP
}

extern "C" void kernel_launch(void* const* d_in, const int* in_sizes, int n_in,
                              void* d_out, int out_size, void* d_ws, size_t ws_size,
                              hipStream_t stream) {
    const float* x   = (const float*)d_in[0];
    const float* a   = (const float*)d_in[1];
    const float* c   = (const float*)d_in[2];
    const float* b1  = (const float*)d_in[3];
    const float* fa1 = (const float*)d_in[4];
    const float* b2  = (const float*)d_in[5];
    const float* fa2 = (const float*)d_in[6];
    float* out = (float*)d_out;

    dim3 grid(B_ * NCHUNK);   // 1024 blocks
    dim3 block(TPB);          // 192 threads = 3 waves
    hipLaunchKernelGGL(biquad4_kernel, grid, block, 0, stream,
                       x, a, c, b1, fa1, b2, fa2, out);
}

// Round 4
// 39.155 us; speedup vs baseline: 1.2480x; 1.2480x over previous
//
#include <hip/hip_runtime.h>

// trainableBiquad4: y = a * biquad2(biquad1(x)) + c
// x: [B=8, S=4096, D=768] f32. Recurrence along S, independent per (b, d).
//
// R3 -> R4: all rounds pin ISSUED vector-memory bytes at ~6.0 TB/s (m13
// copy ceiling) regardless of request width / occupancy / ILP; dur_us =
// issued_bytes / 6 TB/s. Only lever: issue fewer bytes. This is R1's exact
// proven structure (dword, 768 thr, G=4 prefetch) with WARM 64 -> 32
// (ratio 1.5 -> 1.25, issued 251.6 -> 226.5 MB). W=32 numerically
// validated in R3 (pole^32 ~ 5e-9, absmax unchanged).

#define B_ 8
#define S_ 4096
#define D_ 768
#define CHUNK 128
#define WARM 32
#define NCHUNK (S_ / CHUNK)   // 32

__global__ __launch_bounds__(D_, 1) void biquad4_kernel(
    const float* __restrict__ x,
    const float* __restrict__ Ascale,
    const float* __restrict__ Cshift,
    const float* __restrict__ b1,
    const float* __restrict__ fa1,
    const float* __restrict__ b2,
    const float* __restrict__ fa2,
    float* __restrict__ out)
{
    const int d     = threadIdx.x;          // 0..767
    const int blk   = blockIdx.x;           // 0..255
    const int b     = blk / NCHUNK;
    const int chunk = blk % NCHUNK;
    const int cs    = chunk * CHUNK;                  // first output t
    const int t0    = (chunk == 0) ? cs : (cs - WARM); // start (warm-up)
    const int niter = (cs + CHUNK) - t0;              // 128 or 160, both %4==0

    const float a = Ascale[0];
    const float c = Cshift[0];
    const float b10 = b1[d],  b11 = b1[D_ + d],  b12 = b1[2 * D_ + d];
    const float a11 = fa1[d], a12 = fa1[D_ + d];
    const float b20 = b2[d],  b21 = b2[D_ + d],  b22 = b2[2 * D_ + d];
    const float a21 = fa2[d], a22 = fa2[D_ + d];

    const float* __restrict__ xp = x   + ((size_t)b * S_ + t0) * D_ + d;
    float*       __restrict__ op = out + ((size_t)b * S_ + t0) * D_ + d;

    // filter state (zero init; warm-up converges it for chunk>0)
    float x1 = 0.f, x2 = 0.f;   // section-1 input history
    float y1 = 0.f, y2 = 0.f;   // section-1 output history
    float z1 = 0.f, z2 = 0.f;   // section-2 output history

    // 4-deep prefetch pipeline
    float p0 = xp[0 * (size_t)D_];
    float p1 = xp[1 * (size_t)D_];
    float p2 = xp[2 * (size_t)D_];
    float p3 = xp[3 * (size_t)D_];
    xp += 4 * (size_t)D_;

    int t = t0;
    const int ngroup = niter >> 2;
    for (int g = 0; g < ngroup; ++g) {
        float n0 = 0.f, n1 = 0.f, n2 = 0.f, n3 = 0.f;
        if (g + 1 < ngroup) {   // issue next group's loads before computing
            n0 = xp[0 * (size_t)D_];
            n1 = xp[1 * (size_t)D_];
            n2 = xp[2 * (size_t)D_];
            n3 = xp[3 * (size_t)D_];
            xp += 4 * (size_t)D_;
        }

#define STEP(XT)                                                              \
        {                                                                     \
            const float xt = (XT);                                            \
            const float yt = fmaf(b10, xt, fmaf(b11, x1, b12 * x2))           \
                           - fmaf(a11, y1, a12 * y2);                         \
            const float zt = fmaf(b20, yt, fmaf(b21, y1, b22 * y2))           \
                           - fmaf(a21, z1, a22 * z2);                         \
            x2 = x1; x1 = xt;                                                 \
            y2 = y1; y1 = yt;                                                 \
            z2 = z1; z1 = zt;                                                 \
            if (t >= cs) {  /* t is block-uniform: scalar branch */           \
                op[(size_t)(t - t0) * D_] = fmaf(a, zt, c);                   \
            }                                                                 \
            ++t;                                                              \
        }

        STEP(p0); STEP(p1); STEP(p2); STEP(p3);
#undef STEP

        p0 = n0; p1 = n1; p2 = n2; p3 = n3;
    }
}

extern "C" void kernel_launch(void* const* d_in, const int* in_sizes, int n_in,
                              void* d_out, int out_size, void* d_ws, size_t ws_size,
                              hipStream_t stream) {
    const float* x   = (const float*)d_in[0];
    const float* a   = (const float*)d_in[1];
    const float* c   = (const float*)d_in[2];
    const float* b1  = (const float*)d_in[3];
    const float* fa1 = (const float*)d_in[4];
    const float* b2  = (const float*)d_in[5];
    const float* fa2 = (const float*)d_in[6];
    float* out = (float*)d_out;

    dim3 grid(B_ * NCHUNK);   // 256 blocks
    dim3 block(D_);           // 768 threads = 12 waves
    hipLaunchKernelGGL(biquad4_kernel, grid, block, 0, stream,
                       x, a, c, b1, fa1, b2, fa2, out);
}